// Round 8
// baseline (140.288 us; speedup 1.0000x reference)
//
#include <hip/hip_runtime.h>

typedef _Float16 f16;
typedef _Float16 f16x4 __attribute__((ext_vector_type(4)));
typedef _Float16 f16x8 __attribute__((ext_vector_type(8)));
typedef float f32x4 __attribute__((ext_vector_type(4)));

// async global->LDS, 16B per lane; LDS dest = wave-uniform base + lane*16
#define LOADLDS16(gp, lp)                                                     \
  __builtin_amdgcn_global_load_lds(                                           \
      (const __attribute__((address_space(1))) void*)(gp),                    \
      (__attribute__((address_space(3))) void*)(lp), 16, 0, 0)

// ---------------------------------------------------------------------------
// Elementwise cast f32 -> f16 (both activations in one launch)
// ---------------------------------------------------------------------------
__global__ __launch_bounds__(256) void k_cast2(const float* __restrict__ a,
                                               const float* __restrict__ b,
                                               f16* __restrict__ ya,
                                               f16* __restrict__ yb) {
  int i = blockIdx.x * 256 + threadIdx.x;
  const float* x;
  f16* y;
  if (i < 1048576) {
    x = a; y = ya;
  } else {
    x = b; y = yb; i -= 1048576;
  }
  float4 v = reinterpret_cast<const float4*>(x)[i];
  f16x4 o;
  o[0] = (f16)v.x; o[1] = (f16)v.y; o[2] = (f16)v.z; o[3] = (f16)v.w;
  reinterpret_cast<f16x4*>(y)[i] = o;
}

// ---------------------------------------------------------------------------
// Cast + transpose weights: W[1024][1024] f32 -> Wt[N][K] f16  (Wt[n][k]=W[k][n])
// ---------------------------------------------------------------------------
__global__ __launch_bounds__(256) void k_castw_t(
    const float* __restrict__ w0, const float* __restrict__ w1,
    const float* __restrict__ w2, const float* __restrict__ w3,
    f16* __restrict__ o0, f16* __restrict__ o1, f16* __restrict__ o2,
    f16* __restrict__ o3) {
  const float* W;
  f16* O;
  switch (blockIdx.z) {
    case 0: W = w0; O = o0; break;
    case 1: W = w1; O = o1; break;
    case 2: W = w2; O = o2; break;
    default: W = w3; O = o3; break;
  }
  __shared__ f16 T[64][72];
  const int tid = threadIdx.x;
  const int r0 = blockIdx.y * 64, c0 = blockIdx.x * 64;
#pragma unroll
  for (int i = 0; i < 4; ++i) {
    int c = i * 256 + tid;
    int row = c >> 4, col = (c & 15) * 4;
    float4 v = *reinterpret_cast<const float4*>(W + (size_t)(r0 + row) * 1024 + c0 + col);
    T[col + 0][row] = (f16)v.x;
    T[col + 1][row] = (f16)v.y;
    T[col + 2][row] = (f16)v.z;
    T[col + 3][row] = (f16)v.w;
  }
  __syncthreads();
#pragma unroll
  for (int i = 0; i < 2; ++i) {
    int c = i * 256 + tid;
    int cc = c >> 3, ro = (c & 7) * 8;
    f16x8 v;
#pragma unroll
    for (int j = 0; j < 8; ++j) v[j] = T[cc][ro + j];
    *reinterpret_cast<f16x8*>(O + (size_t)(c0 + cc) * 1024 + r0 + ro) = v;
  }
}

// ---------------------------------------------------------------------------
// Fused QKV projection: C[4096, 3072], cols 0-1023 = Xq@Wqt, 1024-2047 =
// Xkv@Wkt, 2048-3071 = Xkv@Wvt. m97 structure: BM=BN=128, BK=64, 4 waves.
// ---------------------------------------------------------------------------
__global__ __launch_bounds__(256) void k_gemm_qkv(const f16* __restrict__ Xq,
                                                  const f16* __restrict__ Xkv,
                                                  const f16* __restrict__ Bt,
                                                  f16* __restrict__ outp) {
  __shared__ f16 As[128 * 64];  // 16 KB
  __shared__ f16 Bs[128 * 64];  // 16 KB
  const int tid = threadIdx.x;
  const int w = tid >> 6, l = tid & 63;
  const int lr = l & 15, lq = l >> 4;
  const int m0 = blockIdx.y * 128, n0 = blockIdx.x * 128;
  const f16* A = (n0 < 1024) ? Xq : Xkv;
  const int wr = (w >> 1) * 64, wc = (w & 1) * 64;
  const int K = 1024;
  f32x4 acc[4][4] = {};
  for (int kt = 0; kt < K; kt += 64) {
#pragma unroll
    for (int i = 0; i < 4; ++i) {
      int c = (i * 4 + w) * 64 + l;
      LOADLDS16(A + (size_t)(m0 + (c >> 3)) * K + kt + (c & 7) * 8,
                As + (size_t)(i * 4 + w) * 512);
      LOADLDS16(Bt + (size_t)(n0 + (c >> 3)) * K + kt + (c & 7) * 8,
                Bs + (size_t)(i * 4 + w) * 512);
    }
    __syncthreads();
#pragma unroll
    for (int kk = 0; kk < 2; ++kk) {
      f16x8 af[4], bf[4];
#pragma unroll
      for (int m = 0; m < 4; ++m)
        af[m] = *reinterpret_cast<const f16x8*>(As + (wr + m * 16 + lr) * 64 + kk * 32 + lq * 8);
#pragma unroll
      for (int n = 0; n < 4; ++n)
        bf[n] = *reinterpret_cast<const f16x8*>(Bs + (wc + n * 16 + lr) * 64 + kk * 32 + lq * 8);
#pragma unroll
      for (int m = 0; m < 4; ++m)
#pragma unroll
        for (int n = 0; n < 4; ++n)
          acc[m][n] = __builtin_amdgcn_mfma_f32_16x16x32_f16(af[m], bf[n], acc[m][n], 0, 0, 0);
    }
    __syncthreads();
  }
#pragma unroll
  for (int m = 0; m < 4; ++m)
#pragma unroll
    for (int n = 0; n < 4; ++n)
#pragma unroll
      for (int r = 0; r < 4; ++r) {
        int row = m0 + wr + m * 16 + lq * 4 + r;
        int col = n0 + wc + n * 16 + lr;
        int b = row >> 10, s = row & 1023;
        int plane = col >> 10, cc = col & 1023;
        int h = cc >> 6, dh = cc & 63;
        outp[(size_t)plane * 4194304 +
             (((size_t)(b * 16 + h)) * 1024 + s) * 64 + dh] = (f16)acc[m][n][r];
      }
}

// ---------------------------------------------------------------------------
// Output GEMM: C[M,N] f32 = A[M,K] @ Bt[N,K]^T. BM=64, BN=128 (512 blocks).
// ---------------------------------------------------------------------------
__global__ __launch_bounds__(256) void k_gemm_o(const f16* __restrict__ A,
                                                const f16* __restrict__ Bt,
                                                float* __restrict__ out, int M,
                                                int N, int K) {
  __shared__ f16 As[64 * 64];
  __shared__ f16 Bs[128 * 64];
  const int tid = threadIdx.x;
  const int w = tid >> 6, l = tid & 63;
  const int lr = l & 15, lq = l >> 4;
  const int m0 = blockIdx.y * 64, n0 = blockIdx.x * 128;
  const int wr = (w >> 1) * 32, wc = (w & 1) * 64;
  f32x4 acc[2][4] = {};
  for (int kt = 0; kt < K; kt += 64) {
#pragma unroll
    for (int i = 0; i < 2; ++i) {
      int c = (i * 4 + w) * 64 + l;
      LOADLDS16(A + (size_t)(m0 + (c >> 3)) * K + kt + (c & 7) * 8,
                As + (size_t)(i * 4 + w) * 512);
    }
#pragma unroll
    for (int i = 0; i < 4; ++i) {
      int c = (i * 4 + w) * 64 + l;
      LOADLDS16(Bt + (size_t)(n0 + (c >> 3)) * K + kt + (c & 7) * 8,
                Bs + (size_t)(i * 4 + w) * 512);
    }
    __syncthreads();
#pragma unroll
    for (int kk = 0; kk < 2; ++kk) {
      f16x8 af[2], bf[4];
#pragma unroll
      for (int m = 0; m < 2; ++m)
        af[m] = *reinterpret_cast<const f16x8*>(As + (wr + m * 16 + lr) * 64 + kk * 32 + lq * 8);
#pragma unroll
      for (int n = 0; n < 4; ++n)
        bf[n] = *reinterpret_cast<const f16x8*>(Bs + (wc + n * 16 + lr) * 64 + kk * 32 + lq * 8);
#pragma unroll
      for (int m = 0; m < 2; ++m)
#pragma unroll
        for (int n = 0; n < 4; ++n)
          acc[m][n] = __builtin_amdgcn_mfma_f32_16x16x32_f16(af[m], bf[n], acc[m][n], 0, 0, 0);
    }
    __syncthreads();
  }
#pragma unroll
  for (int m = 0; m < 2; ++m)
#pragma unroll
    for (int n = 0; n < 4; ++n)
#pragma unroll
      for (int r = 0; r < 4; ++r) {
        int row = m0 + wr + m * 16 + lq * 4 + r;
        int col = n0 + wc + n * 16 + lr;
        out[(size_t)row * N + col] = acc[m][n][r];
      }
}

// ---------------------------------------------------------------------------
// V transpose per head: vb[bh][1024][64] -> vtb[bh][64][1024]
// ---------------------------------------------------------------------------
__global__ __launch_bounds__(256) void k_vtrans(const f16* __restrict__ vb,
                                                f16* __restrict__ vtb) {
  const int bh = blockIdx.y, s0 = blockIdx.x * 64;
  __shared__ f16 T[64][72];
  const int tid = threadIdx.x;
  const f16* src = vb + (size_t)bh * 1024 * 64;
#pragma unroll
  for (int i = 0; i < 2; ++i) {
    int c = i * 256 + tid;
    int row = c >> 3, co = (c & 7) * 8;
    f16x8 v = *reinterpret_cast<const f16x8*>(src + (size_t)(s0 + row) * 64 + co);
#pragma unroll
    for (int j = 0; j < 8; ++j) T[co + j][row] = v[j];
  }
  __syncthreads();
  f16* dst = vtb + (size_t)bh * 64 * 1024;
#pragma unroll
  for (int i = 0; i < 2; ++i) {
    int c = i * 256 + tid;
    int dh = c >> 3, so = (c & 7) * 8;
    f16x8 v;
#pragma unroll
    for (int j = 0; j < 8; ++j) v[j] = T[dh][so + j];
    *reinterpret_cast<f16x8*>(dst + (size_t)dh * 1024 + s0 + so) = v;
  }
}

// ---------------------------------------------------------------------------
// Fused flash attention (T5: scores = QK^T + bias, no 1/sqrt scale).
// v8: counted-vmcnt pipeline (T3+T4) + QBLK=128 (4 waves x 32 q-rows, two
// 16-row fragments each -> 2x arithmetic intensity per K/V LDS byte).
//  - K/V triple-buffered (depth-2 prefetch), bias f32 double-buffered
//    (depth-1). Per wave per iter: issue {4 bias, 2 KV} DMAs.
//  - loop top: s_waitcnt vmcnt(2) (drain tile t's bias+KV, keep t+1's KV
//    in flight; vmcnt decrements in issue order) -> raw s_barrier ->
//    sched_barrier(0). ONE barrier/iter, never vmcnt(0) until last tile.
//  - swapped QK^T: S^T = mfma(K, Q, bias-from-LDS-b128). Defer-max (T13),
//    per-lane rsum, deferred final reduction. All layouts from v7 (verified).
// LDS 66 KB -> 2 blocks/CU; grid 512 = exactly 2/CU, single generation.
// ---------------------------------------------------------------------------
__global__ __launch_bounds__(256, 2) void k_attn(const f16* __restrict__ qb,
                                                 const f16* __restrict__ kb,
                                                 const f16* __restrict__ vtb,
                                                 const float* __restrict__ bias,
                                                 f16* __restrict__ ctx) {
  const int bid = blockIdx.x;
  const int ord = (bid & 7) * 64 + (bid >> 3);  // XCD-chunked: 2 heads/XCD
  const int h = ord >> 5, qt = (ord >> 2) & 7, b = ord & 3;
  const int bh = b * 16 + h;
  const int q0 = qt * 128;
  const int tid = threadIdx.x, w = tid >> 6, l = tid & 63;
  const int lr = l & 15, lq = l >> 4;

  __shared__ f16 Kb3[3][2048];    // [kv=32][dh=64], granule swz g^(row&7)
  __shared__ f16 Vb3[3][2048];    // [dh=64][kv=32], granule swz g^((row>>1)&3)
  __shared__ float Bb2[2][4096];  // [q=128][kv=32] f32, granule swz g^(row&7)
  __shared__ f16 Ps[4][1280];     // per-wave [q=32][kv pad 40]

  // Q fragments: frag A rows w*32+lr, frag B rows w*32+16+lr
  const f16* qp = qb + ((size_t)bh * 1024 + q0 + w * 32 + lr) * 64 + lq * 8;
  f16x8 qA0 = *reinterpret_cast<const f16x8*>(qp);
  f16x8 qA1 = *reinterpret_cast<const f16x8*>(qp + 32);
  f16x8 qB0 = *reinterpret_cast<const f16x8*>(qp + 1024);
  f16x8 qB1 = *reinterpret_cast<const f16x8*>(qp + 1056);

  f32x4 OA[4] = {}, OB[4] = {};
  float mA = -3.0e38f, mB = -3.0e38f, rsA = 0.f, rsB = 0.f;  // q-row = lr

  const f16* kbase = kb + (size_t)bh * 65536;
  const f16* vbase = vtb + (size_t)bh * 65536;
  const float* bbase = bias + ((size_t)h * 1024 + q0) * 1024;

  // staging geometry (wave-uniform LDS dest; pre-swizzled per-lane global src)
  const int krow = w * 8 + (l >> 3), kg = (l & 7) ^ (l >> 3);
  const int vrow = w * 16 + (l >> 2), vg = (l & 3) ^ ((l >> 3) & 3);

  auto stage_kv = [&](int t, int c3) {
    LOADLDS16(kbase + (size_t)(t * 32 + krow) * 64 + kg * 8, &Kb3[c3][w * 512]);
    LOADLDS16(vbase + (size_t)vrow * 1024 + t * 32 + vg * 8, &Vb3[c3][w * 512]);
  };
  auto stage_b = [&](int t, int c2) {
#pragma unroll
    for (int j = 0; j < 4; ++j) {
      int c4 = w * 4 + j;
      int row = c4 * 8 + (l >> 3);
      int gs = (l & 7) ^ (l >> 3);
      LOADLDS16(bbase + (size_t)row * 1024 + t * 32 + gs * 4,
                &Bb2[c2][c4 * 256]);
    }
  };

  // prologue: bias(0) [oldest], KV(0), KV(1) [newest 2]
  stage_b(0, 0);
  stage_kv(0, 0);
  stage_kv(1, 1);

#pragma unroll 1
  for (int t = 0; t < 32; ++t) {
    // drain tile t's loads; keep tile t+1's KV (newest 2) in flight
    if (t < 31) {
      asm volatile("s_waitcnt vmcnt(2)" ::: "memory");
    } else {
      asm volatile("s_waitcnt vmcnt(0)" ::: "memory");
    }
    __builtin_amdgcn_s_barrier();
    __builtin_amdgcn_sched_barrier(0);

    // issue next DMAs: bias depth-1 FIRST, then KV depth-2 (order = vmcnt math)
    if (t + 1 < 32) stage_b(t + 1, (t + 1) & 1);
    if (t + 2 < 32) stage_kv(t + 2, (t + 2) % 3);
    __builtin_amdgcn_sched_barrier(0);

    const int c3 = t % 3, c2 = t & 1;
    const f16* Kc = &Kb3[c3][0];
    const f16* Vc = &Vb3[c3][0];
    const float* Bc = &Bb2[c2][0];

    // ---- S^T init = bias (b128 f32x4: kv = c*16+lq*4..+3 of q-row) ----
    f32x4 S[2][2];
#pragma unroll
    for (int f = 0; f < 2; ++f)
#pragma unroll
      for (int c = 0; c < 2; ++c) {
        int row = w * 32 + f * 16 + lr;
        int pos = (c * 4 + lq) ^ (lr & 7);
        S[f][c] = *reinterpret_cast<const f32x4*>(&Bc[row * 32 + pos * 4]);
      }

    // ---- S^T += K Q^T (K fragments shared by both q-frags) ----
    __builtin_amdgcn_s_setprio(1);
#pragma unroll
    for (int c = 0; c < 2; ++c) {
      int row = c * 16 + lr;
      const f16* kbp = &Kc[row * 64];
      f16x8 kf0 = *reinterpret_cast<const f16x8*>(kbp + ((lq ^ (lr & 7)) * 8));
      f16x8 kf1 = *reinterpret_cast<const f16x8*>(kbp + (((4 + lq) ^ (lr & 7)) * 8));
      S[0][c] = __builtin_amdgcn_mfma_f32_16x16x32_f16(kf0, qA0, S[0][c], 0, 0, 0);
      S[0][c] = __builtin_amdgcn_mfma_f32_16x16x32_f16(kf1, qA1, S[0][c], 0, 0, 0);
      S[1][c] = __builtin_amdgcn_mfma_f32_16x16x32_f16(kf0, qB0, S[1][c], 0, 0, 0);
      S[1][c] = __builtin_amdgcn_mfma_f32_16x16x32_f16(kf1, qB1, S[1][c], 0, 0, 0);
    }
    __builtin_amdgcn_s_setprio(0);

    // ---- defer-max (T13): per-lane bound check, rare reduce+rescale ----
    float tA = fmaxf(fmaxf(fmaxf(S[0][0][0], S[0][0][1]), fmaxf(S[0][0][2], S[0][0][3])),
                     fmaxf(fmaxf(S[0][1][0], S[0][1][1]), fmaxf(S[0][1][2], S[0][1][3])));
    float tB = fmaxf(fmaxf(fmaxf(S[1][0][0], S[1][0][1]), fmaxf(S[1][0][2], S[1][0][3])),
                     fmaxf(fmaxf(S[1][1][0], S[1][1][1]), fmaxf(S[1][1][2], S[1][1][3])));
    bool ok = (tA <= mA + 8.0f) && (tB <= mB + 8.0f);
    if (!__all(ok)) {
      tA = fmaxf(tA, __shfl_xor(tA, 16, 64));
      tA = fmaxf(tA, __shfl_xor(tA, 32, 64));
      tB = fmaxf(tB, __shfl_xor(tB, 16, 64));
      tB = fmaxf(tB, __shfl_xor(tB, 32, 64));
      float mnA = fmaxf(mA, tA), mnB = fmaxf(mB, tB);
      float scA = __expf(mA - mnA), scB = __expf(mB - mnB);
      mA = mnA; mB = mnB;
      rsA *= scA; rsB *= scB;
      int sb = l & 48;
#pragma unroll
      for (int r = 0; r < 4; ++r) {
        float sA = __shfl(scA, sb | (lq * 4 + r), 64);
        float sB = __shfl(scB, sb | (lq * 4 + r), 64);
#pragma unroll
        for (int c = 0; c < 4; ++c) {
          OA[c][r] *= sA;
          OB[c][r] *= sB;
        }
      }
    }

    // ---- P = exp(S - m); per-lane rsum; vectorized b64 spill ----
#pragma unroll
    for (int c = 0; c < 2; ++c) {
      f32x4 pA, pB;
#pragma unroll
      for (int r = 0; r < 4; ++r) {
        pA[r] = __expf(S[0][c][r] - mA);
        pB[r] = __expf(S[1][c][r] - mB);
      }
      rsA += (pA[0] + pA[1]) + (pA[2] + pA[3]);
      rsB += (pB[0] + pB[1]) + (pB[2] + pB[3]);
      f16x4 hA = {(f16)pA[0], (f16)pA[1], (f16)pA[2], (f16)pA[3]};
      f16x4 hB = {(f16)pB[0], (f16)pB[1], (f16)pB[2], (f16)pB[3]};
      *reinterpret_cast<f16x4*>(&Ps[w][lr * 40 + c * 16 + lq * 4]) = hA;
      *reinterpret_cast<f16x4*>(&Ps[w][(16 + lr) * 40 + c * 16 + lq * 4]) = hB;
    }

    // ---- O += P @ V (V fragments shared by both q-frags) ----
    {
      f16x8 paA = *reinterpret_cast<const f16x8*>(&Ps[w][lr * 40 + lq * 8]);
      f16x8 paB = *reinterpret_cast<const f16x8*>(&Ps[w][(16 + lr) * 40 + lq * 8]);
      __builtin_amdgcn_s_setprio(1);
#pragma unroll
      for (int c = 0; c < 4; ++c) {
        int row = c * 16 + lr;
        f16x8 vf = *reinterpret_cast<const f16x8*>(
            &Vc[row * 32 + ((lq ^ ((lr >> 1) & 3)) * 8)]);
        OA[c] = __builtin_amdgcn_mfma_f32_16x16x32_f16(paA, vf, OA[c], 0, 0, 0);
        OB[c] = __builtin_amdgcn_mfma_f32_16x16x32_f16(paB, vf, OB[c], 0, 0, 0);
      }
      __builtin_amdgcn_s_setprio(0);
    }
  }

  // ---- deferred sum reduction across the 4 lq replicas ----
  rsA += __shfl_xor(rsA, 16, 64);
  rsA += __shfl_xor(rsA, 32, 64);
  rsB += __shfl_xor(rsB, 16, 64);
  rsB += __shfl_xor(rsB, 32, 64);
  int sb = l & 48;

  // ---- epilogue: ctx[b][q][h*64+dh] f16 (O rows q=lq*4+r, cols dh=c*16+lr) ----
#pragma unroll
  for (int r = 0; r < 4; ++r) {
    float dA = __shfl(rsA, sb | (lq * 4 + r), 64);
    float dB = __shfl(rsB, sb | (lq * 4 + r), 64);
    int rowA = q0 + w * 32 + lq * 4 + r;
#pragma unroll
    for (int c = 0; c < 4; ++c) {
      int col = h * 64 + c * 16 + lr;
      ctx[((size_t)b * 1024 + rowA) * 1024 + col] = (f16)(OA[c][r] / dA);
      ctx[((size_t)b * 1024 + rowA + 16) * 1024 + col] = (f16)(OB[c][r] / dB);
    }
  }
}

// ---------------------------------------------------------------------------
extern "C" void kernel_launch(void* const* d_in, const int* in_sizes, int n_in,
                              void* d_out, int out_size, void* d_ws,
                              size_t ws_size, hipStream_t stream) {
  const float* input_ids = (const float*)d_in[0];
  const float* enc = (const float*)d_in[1];
  const float* bias = (const float*)d_in[2];
  const float* Wq = (const float*)d_in[3];
  const float* Wk = (const float*)d_in[4];
  const float* Wv = (const float*)d_in[5];
  const float* Wo = (const float*)d_in[6];

  char* ws = (char*)d_ws;
  const size_t MB = 1024 * 1024;
  f16* Xq  = (f16*)(ws + 0 * MB);   // 8 MB; dead after QKV-proj -> reused as ctx
  f16* Xkv = (f16*)(ws + 8 * MB);   // 8 MB; dead after QKV-proj -> reused as vtb
  f16* Wqt = (f16*)(ws + 16 * MB);  // 2 MB each; Wqt|Wkt|Wvt contiguous = [3072][1024]
  f16* Wkt = (f16*)(ws + 18 * MB);
  f16* Wvt = (f16*)(ws + 20 * MB);
  f16* Wot = (f16*)(ws + 22 * MB);
  f16* qbuf = (f16*)(ws + 24 * MB); // 8 MB [bh][s][dh]; kbuf/vbuf planes follow
  f16* kbuf = (f16*)(ws + 32 * MB);
  f16* vbuf = (f16*)(ws + 40 * MB);
  f16* vtb = Xkv;   // [bh][dh][sk]
  f16* ctxb = Xq;   // [4096][1024]

  k_cast2<<<8192, 256, 0, stream>>>(input_ids, enc, Xq, Xkv);
  k_castw_t<<<dim3(16, 16, 4), 256, 0, stream>>>(Wq, Wk, Wv, Wo, Wqt, Wkt, Wvt, Wot);

  // fused Q+K+V projection: N=3072 over [Wqt|Wkt|Wvt], per-block A select
  k_gemm_qkv<<<dim3(24, 32), 256, 0, stream>>>(Xq, Xkv, Wqt, qbuf);

  k_vtrans<<<dim3(16, 64), 256, 0, stream>>>(vbuf, vtb);

  k_attn<<<512, 256, 0, stream>>>(qbuf, kbuf, vtb, bias, ctxb);

  k_gemm_o<<<dim3(8, 64), 256, 0, stream>>>(ctxb, Wot, (float*)d_out, 4096, 1024, 1024);
}